// Round 7
// baseline (188.946 us; speedup 1.0000x reference)
//
#include <hip/hip_runtime.h>

// Raymarcher: R=16384 rays, 64 steps, K=32 prims, template (32,4,16,16,16) f32.
// Round 7: wave-local work compaction, search-free. Lane=(ray-half, prim)
// computes the contiguous inside-step range [i0,i1] (slab), materializes items
// (k,step) as u16 into a private d_ws region, then two balanced item passes:
// alpha pass (w-channel only, 1 LDS atomic/item into per-step buckets) and,
// after an exact per-ray prefix-scan -> contrib table, an rgb pass accumulating
// per-lane r += rgb*contrib (round-6 identity). No binary search, no block
// barriers; LDS 12 KB -> full occupancy.

namespace {

constexpr float kDT  = 1.0f / 64.0f;
constexpr int   kVox = 32 * 4096;                    // (k,z,y,x) voxels

// d_ws layout
constexpr size_t kOffT  = 0;                         // float4[131072] = 2 MiB
constexpr size_t kOffW  = (size_t)2 << 20;           // float[131072] = 512 KiB
constexpr size_t kOffIt = ((size_t)2 << 20) + ((size_t)512 << 10);
constexpr size_t kWsNeed = kOffIt + (size_t)16384 * 2048 * 2;   // + 64 MiB

// ---- pre-pass: (k,c,z,y,x) -> channel-last float4 + dense w-only copy ----
__global__ __launch_bounds__(256) void transpose_tmpl(
    const float* __restrict__ tmpl, float4* __restrict__ wsT,
    float* __restrict__ wsW)
{
    const int idx = blockIdx.x * 256 + threadIdx.x;     // < 131072
    const int k   = idx >> 12;
    const int rem = idx & 4095;
    const float* src = tmpl + k * 16384 + rem;
    float4 v;
    v.x = src[0];
    v.y = src[4096];
    v.z = src[8192];
    v.w = src[12288];
    wsT[idx] = v;
    wsW[idx] = v.w;
}

__global__ __launch_bounds__(256) void raymarch6(
    const float* __restrict__ raypos,
    const float* __restrict__ raydir,
    const float* __restrict__ tminmax,
    const float* __restrict__ primpos,
    const float* __restrict__ primrot,
    const float* __restrict__ primscale,
    const float4* __restrict__ wsT,
    const float* __restrict__ wsW,
    unsigned short* __restrict__ itemsBase,
    float* __restrict__ out, int R)
{
    const int lane = threadIdx.x & 63;
    const int wid  = threadIdx.x >> 6;          // wave 0..3
    const int k    = lane & 31;                 // prim owned by this lane
    const int half = lane >> 5;                 // ray within wave (0/1)
    const int ray  = blockIdx.x * 8 + wid * 2 + half;

    __shared__ float4 sAD[4][2][32][2];         // [wave][half][prim]{A,D}
    __shared__ float  sAlpha[4][2][64];         // per-step alpha-channel sums
    __shared__ float  sContrib[4][2][64];       // per-step contrib after scan

    // zero own wave's buckets (wave-synchronous; DS ops in-order per wave)
    sAlpha[wid][half][k]      = 0.0f;
    sAlpha[wid][half][k + 32] = 0.0f;

    const float rpx = raypos[ray * 3 + 0];
    const float rpy = raypos[ray * 3 + 1];
    const float rpz = raypos[ray * 3 + 2];
    const float rdx = raydir[ray * 3 + 0];
    const float rdy = raydir[ray * 3 + 1];
    const float rdz = raydir[ray * 3 + 2];
    const float tmin = tminmax[ray * 2 + 0];
    const float tmax = tminmax[ray * 2 + 1];

    // largest valid step: tmin + i*DT < tmax
    int last = min(63, (int)floorf((tmax - tmin) * 64.0f));
    if (last >= 0 && fmaf((float)last, kDT, tmin) >= tmax) last--;

    // ---- phase 0: affine fold + slab step range (verified r1-r6 math) ----
    int i0, len;
    {
        const float ox = rpx - primpos[k * 3 + 0];
        const float oy = rpy - primpos[k * 3 + 1];
        const float oz = rpz - primpos[k * 3 + 2];
        float a[3], d[3];
        float lo = -1e30f, hi = 1e30f;
        #pragma unroll
        for (int i = 0; i < 3; ++i) {
            const float r0 = primrot[k * 9 + 3 * i + 0];
            const float r1 = primrot[k * 9 + 3 * i + 1];
            const float r2 = primrot[k * 9 + 3 * i + 2];
            const float sci = primscale[k * 3 + i];
            a[i] = (r0 * ox + r1 * oy + r2 * oz) * sci;
            d[i] = (r0 * rdx + r1 * rdy + r2 * rdz) * sci;
            const float inv = 1.0f / d[i];
            const float tA = (-1.001f - a[i]) * inv;
            const float tB = ( 1.001f - a[i]) * inv;
            lo = fmaxf(lo, fminf(tA, tB));
            hi = fminf(hi, fmaxf(tA, tB));
        }
        i0 = max(0,    (int)ceilf ((lo - tmin) * 64.0f));
        const int i1 = min(last, (int)floorf((hi - tmin) * 64.0f));
        len = max(0, i1 - i0 + 1);
        sAD[wid][half][k][0] = make_float4(a[0], a[1], a[2], 0.0f);
        sAD[wid][half][k][1] = make_float4(d[0], d[1], d[2], 0.0f);
    }

    // ---- phase 1: half-local scan of len -> offsets; materialize items ----
    int psum = len;
    #pragma unroll
    for (int m = 1; m < 32; m <<= 1) {
        const int n = __shfl_up(psum, m);
        if (k >= m) psum += n;
    }
    const int off   = psum - len;
    const int total = __shfl(psum, lane | 31);   // sum at last lane of own half

    unsigned short* items = itemsBase + (size_t)ray * 2048;
    for (int j = 0; j < len; ++j)
        items[off + j] = (unsigned short)((k << 6) | (i0 + j));

    // ---- phase 2: alpha pass over items (w channel only) ----
    for (int jj = k; jj < total; jj += 32) {
        const int it   = items[jj];
        const int k2   = it >> 6;
        const int step = it & 63;
        const float4 A = sAD[wid][half][k2][0];
        const float4 D = sAD[wid][half][k2][1];
        const float t  = fmaf((float)step, kDT, tmin);
        const float y0 = fmaf(D.x, t, A.x);
        const float y1 = fmaf(D.y, t, A.y);
        const float y2 = fmaf(D.z, t, A.z);
        if (fabsf(y0) <= 1.0f && fabsf(y1) <= 1.0f && fabsf(y2) <= 1.0f) {
            const float gz = (y0 + 1.0f) * 7.5f;
            const float gy = (y1 + 1.0f) * 7.5f;
            const float gx = (y2 + 1.0f) * 7.5f;
            const int iz = (int)fminf(floorf(gz), 14.0f);
            const int iy = (int)fminf(floorf(gy), 14.0f);
            const int ix = (int)fminf(floorf(gx), 14.0f);
            const float fz = fminf(gz - (float)iz, 1.0f);
            const float fy = fminf(gy - (float)iy, 1.0f);
            const float fx = fminf(gx - (float)ix, 1.0f);
            const float oz_ = 1.0f - fz, oy_ = 1.0f - fy, ox_ = 1.0f - fx;
            const float* w = wsW + (k2 * 4096 + iz * 256 + iy * 16 + ix);
            const float s3 = (oz_ * oy_ * ox_) * w[0]   + (oz_ * oy_ * fx) * w[1]
                           + (oz_ * fy  * ox_) * w[16]  + (oz_ * fy  * fx) * w[17]
                           + (fz  * oy_ * ox_) * w[256] + (fz  * oy_ * fx) * w[257]
                           + (fz  * fy  * ox_) * w[272] + (fz  * fy  * fx) * w[273];
            atomicAdd(&sAlpha[wid][half][step], s3);
        }
    }

    // ---- phase 3: per-ray exact alpha scan -> contrib table ----
    float alphaOut = 0.0f;
    #pragma unroll
    for (int r = 0; r < 2; ++r) {
        const float tminR = __shfl(tmin, r * 32);
        const float tmaxR = __shfl(tmax, r * 32);
        const float b  = sAlpha[wid][r][lane];
        const float tl = fmaf((float)lane, kDT, tminR);
        const float aa = (tl < tmaxR) ? b * kDT : 0.0f;
        float ps = aa;
        #pragma unroll
        for (int m = 1; m < 64; m <<= 1) {
            const float n = __shfl_up(ps, m);
            if (lane >= m) ps += n;
        }
        const float aI = fminf(ps, 1.0f);               // increments >= 0
        sContrib[wid][r][lane] = aI - fminf(ps - aa, 1.0f);
        const float aEnd = __shfl(aI, 63);
        if (half == r) alphaOut = aEnd;
    }

    // ---- phase 4: rgb pass over items, per-lane weighted accumulation ----
    float r0 = 0.0f, r1 = 0.0f, r2 = 0.0f;
    for (int jj = k; jj < total; jj += 32) {
        const int it   = items[jj];
        const int k2   = it >> 6;
        const int step = it & 63;
        const float contrib = sContrib[wid][half][step];
        if (contrib == 0.0f) continue;                  // saturated/empty step
        const float4 A = sAD[wid][half][k2][0];
        const float4 D = sAD[wid][half][k2][1];
        const float t  = fmaf((float)step, kDT, tmin);
        const float y0 = fmaf(D.x, t, A.x);
        const float y1 = fmaf(D.y, t, A.y);
        const float y2 = fmaf(D.z, t, A.z);
        if (fabsf(y0) <= 1.0f && fabsf(y1) <= 1.0f && fabsf(y2) <= 1.0f) {
            const float gz = (y0 + 1.0f) * 7.5f;
            const float gy = (y1 + 1.0f) * 7.5f;
            const float gx = (y2 + 1.0f) * 7.5f;
            const int iz = (int)fminf(floorf(gz), 14.0f);
            const int iy = (int)fminf(floorf(gy), 14.0f);
            const int ix = (int)fminf(floorf(gx), 14.0f);
            const float fz = fminf(gz - (float)iz, 1.0f);
            const float fy = fminf(gy - (float)iy, 1.0f);
            const float fx = fminf(gx - (float)ix, 1.0f);
            const float oz_ = 1.0f - fz, oy_ = 1.0f - fy, ox_ = 1.0f - fx;
            const float w000 = oz_ * oy_ * ox_;
            const float w001 = oz_ * oy_ * fx;
            const float w010 = oz_ * fy  * ox_;
            const float w011 = oz_ * fy  * fx;
            const float w100 = fz  * oy_ * ox_;
            const float w101 = fz  * oy_ * fx;
            const float w110 = fz  * fy  * ox_;
            const float w111 = fz  * fy  * fx;
            const float4* tp = wsT + (k2 * 4096 + iz * 256 + iy * 16 + ix);
            const float4 c000 = tp[0];
            const float4 c001 = tp[1];
            const float4 c010 = tp[16];
            const float4 c011 = tp[17];
            const float4 c100 = tp[256];
            const float4 c101 = tp[257];
            const float4 c110 = tp[272];
            const float4 c111 = tp[273];
            const float v0 = w000*c000.x + w001*c001.x + w010*c010.x + w011*c011.x
                           + w100*c100.x + w101*c101.x + w110*c110.x + w111*c111.x;
            const float v1 = w000*c000.y + w001*c001.y + w010*c010.y + w011*c011.y
                           + w100*c100.y + w101*c101.y + w110*c110.y + w111*c111.y;
            const float v2 = w000*c000.z + w001*c001.z + w010*c010.z + w011*c011.z
                           + w100*c100.z + w101*c101.z + w110*c110.z + w111*c111.z;
            r0 = fmaf(v0, contrib, r0);
            r1 = fmaf(v1, contrib, r1);
            r2 = fmaf(v2, contrib, r2);
        }
    }

    // final half-local reduce of rgb partials
    #pragma unroll
    for (int m = 1; m < 32; m <<= 1) {
        r0 += __shfl_xor(r0, m);
        r1 += __shfl_xor(r1, m);
        r2 += __shfl_xor(r2, m);
    }

    if (k == 0) {
        out[0 * R + ray] = r0;
        out[1 * R + ray] = r1;
        out[2 * R + ray] = r2;
        out[3 * R + ray] = alphaOut;
        out[4 * R + ray] = r0;
        out[5 * R + ray] = r1;
        out[6 * R + ray] = r2;
        out[7 * R + ray] = alphaOut;
    }
}

// ---- fallback (round-6 kernel, original template layout) for small ws ----
__global__ __launch_bounds__(256) void raymarch_fb(
    const float* __restrict__ raypos, const float* __restrict__ raydir,
    const float* __restrict__ tminmax, const float* __restrict__ primpos,
    const float* __restrict__ primrot, const float* __restrict__ primscale,
    const float* __restrict__ tmpl, float* __restrict__ out, int R)
{
    const int lane = threadIdx.x & 63;
    const int wid  = threadIdx.x >> 6;
    const int k    = lane & 31;
    const int half = lane >> 5;
    const int ray  = blockIdx.x * 8 + wid * 2 + half;

    const float rpx = raypos[ray*3+0], rpy = raypos[ray*3+1], rpz = raypos[ray*3+2];
    const float rdx = raydir[ray*3+0], rdy = raydir[ray*3+1], rdz = raydir[ray*3+2];
    const float tmin = tminmax[ray*2+0], tmax = tminmax[ray*2+1];

    float A0,A1,A2,D0,D1,D2;
    {
        const float ox = rpx - primpos[k*3+0], oy = rpy - primpos[k*3+1], oz = rpz - primpos[k*3+2];
        const float s0 = primscale[k*3+0], s1 = primscale[k*3+1], s2 = primscale[k*3+2];
        const float* rk = primrot + k*9;
        A0 = (rk[0]*ox+rk[1]*oy+rk[2]*oz)*s0; D0 = (rk[0]*rdx+rk[1]*rdy+rk[2]*rdz)*s0;
        A1 = (rk[3]*ox+rk[4]*oy+rk[5]*oz)*s1; D1 = (rk[3]*rdx+rk[4]*rdy+rk[5]*rdz)*s1;
        A2 = (rk[6]*ox+rk[7]*oy+rk[8]*oz)*s2; D2 = (rk[6]*rdx+rk[7]*rdy+rk[8]*rdz)*s2;
    }
    float alpha = 0.f, r0 = 0.f, r1 = 0.f, r2 = 0.f;
    for (int i = 0; i < 64; ++i) {
        const float t = fmaf((float)i, kDT, tmin);
        const bool live = (t < tmax) && (alpha < 1.0f);
        if (__ballot(live) == 0ull) break;
        const float y0 = fmaf(D0,t,A0), y1 = fmaf(D1,t,A1), y2 = fmaf(D2,t,A2);
        const bool inside = live && fabsf(y0)<=1.f && fabsf(y1)<=1.f && fabsf(y2)<=1.f;
        if (__ballot(inside) == 0ull) continue;
        float s0=0.f,s1=0.f,s2=0.f,s3=0.f;
        if (inside) {
            const float gz=(y0+1.f)*7.5f, gy=(y1+1.f)*7.5f, gx=(y2+1.f)*7.5f;
            const int iz=(int)fminf(floorf(gz),14.f), iy=(int)fminf(floorf(gy),14.f), ix=(int)fminf(floorf(gx),14.f);
            const float fz=fminf(gz-(float)iz,1.f), fy=fminf(gy-(float)iy,1.f), fx=fminf(gx-(float)ix,1.f);
            const float oz_=1.f-fz, oy_=1.f-fy, ox_=1.f-fx;
            const float w000=oz_*oy_*ox_, w001=oz_*oy_*fx, w010=oz_*fy*ox_, w011=oz_*fy*fx;
            const float w100=fz*oy_*ox_, w101=fz*oy_*fx, w110=fz*fy*ox_, w111=fz*fy*fx;
            const float* tp = tmpl + k*16384 + iz*256 + iy*16 + ix;
            float acc[4];
            #pragma unroll
            for (int c = 0; c < 4; ++c) {
                const float* tc = tp + c*4096;
                acc[c] = w000*tc[0]+w001*tc[1]+w010*tc[16]+w011*tc[17]
                       + w100*tc[256]+w101*tc[257]+w110*tc[272]+w111*tc[273];
            }
            s0=acc[0]; s1=acc[1]; s2=acc[2]; s3=acc[3];
        }
        float tot3 = s3;
        #pragma unroll
        for (int m = 1; m < 32; m <<= 1) tot3 += __shfl_xor(tot3, m);
        const float na = fminf(fmaf(tot3, kDT, alpha), 1.0f);
        const float contrib = na - alpha;
        alpha = na;
        r0 = fmaf(s0, contrib, r0); r1 = fmaf(s1, contrib, r1); r2 = fmaf(s2, contrib, r2);
    }
    #pragma unroll
    for (int m = 1; m < 32; m <<= 1) {
        r0 += __shfl_xor(r0, m); r1 += __shfl_xor(r1, m); r2 += __shfl_xor(r2, m);
    }
    if (k == 0) {
        out[0*R+ray]=r0; out[1*R+ray]=r1; out[2*R+ray]=r2; out[3*R+ray]=alpha;
        out[4*R+ray]=r0; out[5*R+ray]=r1; out[6*R+ray]=r2; out[7*R+ray]=alpha;
    }
}

} // namespace

extern "C" void kernel_launch(void* const* d_in, const int* in_sizes, int n_in,
                              void* d_out, int out_size, void* d_ws, size_t ws_size,
                              hipStream_t stream) {
    const float* raypos    = (const float*)d_in[0];
    const float* raydir    = (const float*)d_in[1];
    const float* tminmax   = (const float*)d_in[2];
    const float* primpos   = (const float*)d_in[3];
    const float* primrot   = (const float*)d_in[4];
    const float* primscale = (const float*)d_in[5];
    const float* tmpl      = (const float*)d_in[6];
    float* out = (float*)d_out;

    const int R = in_sizes[0] / 3;   // 16384

    if (ws_size >= kWsNeed) {
        float4* wsT = (float4*)((char*)d_ws + kOffT);
        float*  wsW = (float*)((char*)d_ws + kOffW);
        unsigned short* items = (unsigned short*)((char*)d_ws + kOffIt);
        transpose_tmpl<<<dim3(kVox / 256), dim3(256), 0, stream>>>(tmpl, wsT, wsW);
        raymarch6<<<dim3(R / 8), dim3(256), 0, stream>>>(
            raypos, raydir, tminmax, primpos, primrot, primscale,
            wsT, wsW, items, out, R);
    } else {
        raymarch_fb<<<dim3(R / 8), dim3(256), 0, stream>>>(
            raypos, raydir, tminmax, primpos, primrot, primscale, tmpl, out, R);
    }
}

// Round 8
// 97.273 us; speedup vs baseline: 1.9424x; 1.9424x over previous
//
#include <hip/hip_runtime.h>
#include <hip/hip_fp16.h>

// Raymarcher: R=16384 rays, 64 steps, K=32 prims, template (32,4,16,16,16) f32.
// Round 8: round-6 control flow (32 lanes/ray, 1 prim/lane, 2048 blocks,
// alpha-only per-step reduce, per-lane rgb accumulation) + fp16 channel-last
// template (corner = 8 B, halves the L2 bytes/eval that bound round 6) and
// v_pk_fma_f16 corner accumulation (16 pk-FMA vs 32 f32 FMA).

namespace {

constexpr float kDT  = 1.0f / 64.0f;
constexpr int   kVox = 32 * 4096;   // (k,z,y,x) voxel count

struct H4 { __half2 lo, hi; };      // one voxel: (r,g) (b,a) - 8 bytes

// ---- pre-pass: (k,c,z,y,x) f32 -> (k,z,y,x,c) fp16 ----
__global__ __launch_bounds__(256) void transpose_tmpl_h(
    const float* __restrict__ tmpl, H4* __restrict__ wsH)
{
    const int idx = blockIdx.x * 256 + threadIdx.x;     // < 131072
    const int k   = idx >> 12;
    const int rem = idx & 4095;
    const float* src = tmpl + k * 16384 + rem;
    H4 v;
    v.lo = __floats2half2_rn(src[0],    src[4096]);
    v.hi = __floats2half2_rn(src[8192], src[12288]);
    wsH[idx] = v;
}

__global__ __launch_bounds__(256) void raymarch7(
    const float* __restrict__ raypos,
    const float* __restrict__ raydir,
    const float* __restrict__ tminmax,
    const float* __restrict__ primpos,
    const float* __restrict__ primrot,
    const float* __restrict__ primscale,
    const H4* __restrict__ wsH,
    float* __restrict__ out,
    int R)
{
    const int lane = threadIdx.x & 63;
    const int wid  = threadIdx.x >> 6;          // wave 0..3
    const int k    = lane & 31;                 // prim owned by this lane
    const int half = lane >> 5;                 // ray within wave
    const int ray  = blockIdx.x * 8 + wid * 2 + half;

    const float rpx = raypos[ray * 3 + 0];
    const float rpy = raypos[ray * 3 + 1];
    const float rpz = raypos[ray * 3 + 2];
    const float rdx = raydir[ray * 3 + 0];
    const float rdy = raydir[ray * 3 + 1];
    const float rdz = raydir[ray * 3 + 2];
    const float tmin = tminmax[ray * 2 + 0];
    const float tmax = tminmax[ray * 2 + 1];

    // Fold prim k into affine y_i(t) = A_i + D_i * t (verified r1-r7 math).
    float A0, A1, A2, D0, D1, D2;
    {
        const float ox = rpx - primpos[k * 3 + 0];
        const float oy = rpy - primpos[k * 3 + 1];
        const float oz = rpz - primpos[k * 3 + 2];
        const float s0 = primscale[k * 3 + 0];
        const float s1 = primscale[k * 3 + 1];
        const float s2 = primscale[k * 3 + 2];
        const float* rk = primrot + k * 9;
        A0 = (rk[0] * ox + rk[1] * oy + rk[2] * oz) * s0;
        D0 = (rk[0] * rdx + rk[1] * rdy + rk[2] * rdz) * s0;
        A1 = (rk[3] * ox + rk[4] * oy + rk[5] * oz) * s1;
        D1 = (rk[3] * rdx + rk[4] * rdy + rk[5] * rdz) * s1;
        A2 = (rk[6] * ox + rk[7] * oy + rk[8] * oz) * s2;
        D2 = (rk[6] * rdx + rk[7] * rdy + rk[8] * rdz) * s2;
    }

    float alpha = 0.f;
    float r0 = 0.f, r1 = 0.f, r2 = 0.f;   // per-lane rgb partials

    for (int i = 0; i < 64; ++i) {
        const float t = fmaf((float)i, kDT, tmin);
        const bool live = (t < tmax) && (alpha < 1.0f);
        if (__ballot(live) == 0ull) break;

        const float y0 = fmaf(D0, t, A0);
        const float y1 = fmaf(D1, t, A1);
        const float y2 = fmaf(D2, t, A2);
        const bool inside = live && fabsf(y0) <= 1.0f && fabsf(y1) <= 1.0f
                                 && fabsf(y2) <= 1.0f;
        if (__ballot(inside) == 0ull) continue;

        float s0 = 0.f, s1 = 0.f, s2 = 0.f, s3 = 0.f;
        if (inside) {
            const float gz = (y0 + 1.0f) * 7.5f;
            const float gy = (y1 + 1.0f) * 7.5f;
            const float gx = (y2 + 1.0f) * 7.5f;
            const int iz = (int)fminf(floorf(gz), 14.0f);
            const int iy = (int)fminf(floorf(gy), 14.0f);
            const int ix = (int)fminf(floorf(gx), 14.0f);
            const float fz = fminf(gz - (float)iz, 1.0f);
            const float fy = fminf(gy - (float)iy, 1.0f);
            const float fx = fminf(gx - (float)ix, 1.0f);
            const float oz_ = 1.0f - fz, oy_ = 1.0f - fy, ox_ = 1.0f - fx;
            const float w000 = oz_ * oy_ * ox_;
            const float w001 = oz_ * oy_ * fx;
            const float w010 = oz_ * fy  * ox_;
            const float w011 = oz_ * fy  * fx;
            const float w100 = fz  * oy_ * ox_;
            const float w101 = fz  * oy_ * fx;
            const float w110 = fz  * fy  * ox_;
            const float w111 = fz  * fy  * fx;

            const H4* tp = wsH + (k * 4096 + iz * 256 + iy * 16 + ix);
            const H4 c000 = tp[0];
            const H4 c001 = tp[1];
            const H4 c010 = tp[16];
            const H4 c011 = tp[17];
            const H4 c100 = tp[256];
            const H4 c101 = tp[257];
            const H4 c110 = tp[272];
            const H4 c111 = tp[273];

            // packed fp16 accumulation: accLo=(r,g), accHi=(b,a)
            __half2 accLo = __hmul2(__float2half2_rn(w000), c000.lo);
            __half2 accHi = __hmul2(__float2half2_rn(w000), c000.hi);
            __half2 wh;
            wh = __float2half2_rn(w001);
            accLo = __hfma2(wh, c001.lo, accLo); accHi = __hfma2(wh, c001.hi, accHi);
            wh = __float2half2_rn(w010);
            accLo = __hfma2(wh, c010.lo, accLo); accHi = __hfma2(wh, c010.hi, accHi);
            wh = __float2half2_rn(w011);
            accLo = __hfma2(wh, c011.lo, accLo); accHi = __hfma2(wh, c011.hi, accHi);
            wh = __float2half2_rn(w100);
            accLo = __hfma2(wh, c100.lo, accLo); accHi = __hfma2(wh, c100.hi, accHi);
            wh = __float2half2_rn(w101);
            accLo = __hfma2(wh, c101.lo, accLo); accHi = __hfma2(wh, c101.hi, accHi);
            wh = __float2half2_rn(w110);
            accLo = __hfma2(wh, c110.lo, accLo); accHi = __hfma2(wh, c110.hi, accHi);
            wh = __float2half2_rn(w111);
            accLo = __hfma2(wh, c111.lo, accLo); accHi = __hfma2(wh, c111.hi, accHi);

            const float2 fLo = __half22float2(accLo);
            const float2 fHi = __half22float2(accHi);
            s0 = fLo.x; s1 = fLo.y; s2 = fHi.x; s3 = fHi.y;
        }

        // alpha-channel cross-lane reduce (masks < 32 stay within the half)
        float tot3 = s3;
        #pragma unroll
        for (int m = 1; m < 32; m <<= 1) tot3 += __shfl_xor(tot3, m);

        const float na = fminf(fmaf(tot3, kDT, alpha), 1.0f);  // tot3 >= 0
        const float contrib = na - alpha;
        alpha = na;
        r0 = fmaf(s0, contrib, r0);
        r1 = fmaf(s1, contrib, r1);
        r2 = fmaf(s2, contrib, r2);
    }

    #pragma unroll
    for (int m = 1; m < 32; m <<= 1) {
        r0 += __shfl_xor(r0, m);
        r1 += __shfl_xor(r1, m);
        r2 += __shfl_xor(r2, m);
    }

    if (k == 0) {
        out[0 * R + ray] = r0;
        out[1 * R + ray] = r1;
        out[2 * R + ray] = r2;
        out[3 * R + ray] = alpha;
        out[4 * R + ray] = r0;
        out[5 * R + ray] = r1;
        out[6 * R + ray] = r2;
        out[7 * R + ray] = alpha;
    }
}

// ---- fallback (round-6 kernel, original f32 template) for tiny ws ----
__global__ __launch_bounds__(256) void raymarch_fb(
    const float* __restrict__ raypos, const float* __restrict__ raydir,
    const float* __restrict__ tminmax, const float* __restrict__ primpos,
    const float* __restrict__ primrot, const float* __restrict__ primscale,
    const float* __restrict__ tmpl, float* __restrict__ out, int R)
{
    const int lane = threadIdx.x & 63;
    const int wid  = threadIdx.x >> 6;
    const int k    = lane & 31;
    const int half = lane >> 5;
    const int ray  = blockIdx.x * 8 + wid * 2 + half;

    const float rpx = raypos[ray*3+0], rpy = raypos[ray*3+1], rpz = raypos[ray*3+2];
    const float rdx = raydir[ray*3+0], rdy = raydir[ray*3+1], rdz = raydir[ray*3+2];
    const float tmin = tminmax[ray*2+0], tmax = tminmax[ray*2+1];

    float A0,A1,A2,D0,D1,D2;
    {
        const float ox = rpx - primpos[k*3+0], oy = rpy - primpos[k*3+1], oz = rpz - primpos[k*3+2];
        const float s0 = primscale[k*3+0], s1 = primscale[k*3+1], s2 = primscale[k*3+2];
        const float* rk = primrot + k*9;
        A0 = (rk[0]*ox+rk[1]*oy+rk[2]*oz)*s0; D0 = (rk[0]*rdx+rk[1]*rdy+rk[2]*rdz)*s0;
        A1 = (rk[3]*ox+rk[4]*oy+rk[5]*oz)*s1; D1 = (rk[3]*rdx+rk[4]*rdy+rk[5]*rdz)*s1;
        A2 = (rk[6]*ox+rk[7]*oy+rk[8]*oz)*s2; D2 = (rk[6]*rdx+rk[7]*rdy+rk[8]*rdz)*s2;
    }
    float alpha = 0.f, r0 = 0.f, r1 = 0.f, r2 = 0.f;
    for (int i = 0; i < 64; ++i) {
        const float t = fmaf((float)i, kDT, tmin);
        const bool live = (t < tmax) && (alpha < 1.0f);
        if (__ballot(live) == 0ull) break;
        const float y0 = fmaf(D0,t,A0), y1 = fmaf(D1,t,A1), y2 = fmaf(D2,t,A2);
        const bool inside = live && fabsf(y0)<=1.f && fabsf(y1)<=1.f && fabsf(y2)<=1.f;
        if (__ballot(inside) == 0ull) continue;
        float s0=0.f,s1=0.f,s2=0.f,s3=0.f;
        if (inside) {
            const float gz=(y0+1.f)*7.5f, gy=(y1+1.f)*7.5f, gx=(y2+1.f)*7.5f;
            const int iz=(int)fminf(floorf(gz),14.f), iy=(int)fminf(floorf(gy),14.f), ix=(int)fminf(floorf(gx),14.f);
            const float fz=fminf(gz-(float)iz,1.f), fy=fminf(gy-(float)iy,1.f), fx=fminf(gx-(float)ix,1.f);
            const float oz_=1.f-fz, oy_=1.f-fy, ox_=1.f-fx;
            const float w000=oz_*oy_*ox_, w001=oz_*oy_*fx, w010=oz_*fy*ox_, w011=oz_*fy*fx;
            const float w100=fz*oy_*ox_, w101=fz*oy_*fx, w110=fz*fy*ox_, w111=fz*fy*fx;
            const float* tp = tmpl + k*16384 + iz*256 + iy*16 + ix;
            float acc[4];
            #pragma unroll
            for (int c = 0; c < 4; ++c) {
                const float* tc = tp + c*4096;
                acc[c] = w000*tc[0]+w001*tc[1]+w010*tc[16]+w011*tc[17]
                       + w100*tc[256]+w101*tc[257]+w110*tc[272]+w111*tc[273];
            }
            s0=acc[0]; s1=acc[1]; s2=acc[2]; s3=acc[3];
        }
        float tot3 = s3;
        #pragma unroll
        for (int m = 1; m < 32; m <<= 1) tot3 += __shfl_xor(tot3, m);
        const float na = fminf(fmaf(tot3, kDT, alpha), 1.0f);
        const float contrib = na - alpha;
        alpha = na;
        r0 = fmaf(s0, contrib, r0); r1 = fmaf(s1, contrib, r1); r2 = fmaf(s2, contrib, r2);
    }
    #pragma unroll
    for (int m = 1; m < 32; m <<= 1) {
        r0 += __shfl_xor(r0, m); r1 += __shfl_xor(r1, m); r2 += __shfl_xor(r2, m);
    }
    if (k == 0) {
        out[0*R+ray]=r0; out[1*R+ray]=r1; out[2*R+ray]=r2; out[3*R+ray]=alpha;
        out[4*R+ray]=r0; out[5*R+ray]=r1; out[6*R+ray]=r2; out[7*R+ray]=alpha;
    }
}

} // namespace

extern "C" void kernel_launch(void* const* d_in, const int* in_sizes, int n_in,
                              void* d_out, int out_size, void* d_ws, size_t ws_size,
                              hipStream_t stream) {
    const float* raypos    = (const float*)d_in[0];
    const float* raydir    = (const float*)d_in[1];
    const float* tminmax   = (const float*)d_in[2];
    const float* primpos   = (const float*)d_in[3];
    const float* primrot   = (const float*)d_in[4];
    const float* primscale = (const float*)d_in[5];
    const float* tmpl      = (const float*)d_in[6];
    float* out = (float*)d_out;

    const int R = in_sizes[0] / 3;   // 16384
    const size_t needH = (size_t)kVox * sizeof(H4);   // 1 MiB

    if (ws_size >= needH) {
        H4* wsH = (H4*)d_ws;
        transpose_tmpl_h<<<dim3(kVox / 256), dim3(256), 0, stream>>>(tmpl, wsH);
        raymarch7<<<dim3(R / 8), dim3(256), 0, stream>>>(
            raypos, raydir, tminmax, primpos, primrot, primscale, wsH, out, R);
    } else {
        raymarch_fb<<<dim3(R / 8), dim3(256), 0, stream>>>(
            raypos, raydir, tminmax, primpos, primrot, primscale, tmpl, out, R);
    }
}

// Round 9
// 97.147 us; speedup vs baseline: 1.9449x; 1.0013x over previous
//
#include <hip/hip_runtime.h>
#include <hip/hip_fp16.h>

// Raymarcher: R=16384 rays, 64 steps, K=32 prims, template (32,4,16,16,16) f32.
// Round 9: r6/r8 structure (32 lanes/ray, 1 prim/lane, 2048 blocks, alpha-only
// per-step reduce, per-lane rgb accumulation, fp16 channel-last template) with
// a slimmed trilinear block: factorized packed-fp16 lerp (z->y->x), g via one
// fma (sign-safe), trunc-based cell index, hoisted template base. ~20% fewer
// VALU inst/eval on a VALU-issue-bound kernel (r8 showed bytes are not the
// limiter: halving them bought only ~5us).

namespace {

constexpr float kDT  = 1.0f / 64.0f;
constexpr int   kVox = 32 * 4096;   // (k,z,y,x) voxel count

struct H4 { __half2 lo, hi; };      // one voxel: (r,g) (b,a) - 8 bytes

// ---- pre-pass: (k,c,z,y,x) f32 -> (k,z,y,x,c) fp16 ----
__global__ __launch_bounds__(256) void transpose_tmpl_h(
    const float* __restrict__ tmpl, H4* __restrict__ wsH)
{
    const int idx = blockIdx.x * 256 + threadIdx.x;     // < 131072
    const int k   = idx >> 12;
    const int rem = idx & 4095;
    const float* src = tmpl + k * 16384 + rem;
    H4 v;
    v.lo = __floats2half2_rn(src[0],    src[4096]);
    v.hi = __floats2half2_rn(src[8192], src[12288]);
    wsH[idx] = v;
}

__device__ __forceinline__ __half2 lerp2(__half2 a, __half2 b, __half2 f) {
    return __hfma2(f, __hsub2(b, a), a);
}

__global__ __launch_bounds__(256) void raymarch8(
    const float* __restrict__ raypos,
    const float* __restrict__ raydir,
    const float* __restrict__ tminmax,
    const float* __restrict__ primpos,
    const float* __restrict__ primrot,
    const float* __restrict__ primscale,
    const H4* __restrict__ wsH,
    float* __restrict__ out,
    int R)
{
    const int lane = threadIdx.x & 63;
    const int wid  = threadIdx.x >> 6;          // wave 0..3
    const int k    = lane & 31;                 // prim owned by this lane
    const int half = lane >> 5;                 // ray within wave
    const int ray  = blockIdx.x * 8 + wid * 2 + half;

    const float rpx = raypos[ray * 3 + 0];
    const float rpy = raypos[ray * 3 + 1];
    const float rpz = raypos[ray * 3 + 2];
    const float rdx = raydir[ray * 3 + 0];
    const float rdy = raydir[ray * 3 + 1];
    const float rdz = raydir[ray * 3 + 2];
    const float tmin = tminmax[ray * 2 + 0];
    const float tmax = tminmax[ray * 2 + 1];

    // Fold prim k into affine y_i(t) = A_i + D_i * t (verified r1-r8 math).
    float A0, A1, A2, D0, D1, D2;
    {
        const float ox = rpx - primpos[k * 3 + 0];
        const float oy = rpy - primpos[k * 3 + 1];
        const float oz = rpz - primpos[k * 3 + 2];
        const float s0 = primscale[k * 3 + 0];
        const float s1 = primscale[k * 3 + 1];
        const float s2 = primscale[k * 3 + 2];
        const float* rk = primrot + k * 9;
        A0 = (rk[0] * ox + rk[1] * oy + rk[2] * oz) * s0;
        D0 = (rk[0] * rdx + rk[1] * rdy + rk[2] * rdz) * s0;
        A1 = (rk[3] * ox + rk[4] * oy + rk[5] * oz) * s1;
        D1 = (rk[3] * rdx + rk[4] * rdy + rk[5] * rdz) * s1;
        A2 = (rk[6] * ox + rk[7] * oy + rk[8] * oz) * s2;
        D2 = (rk[6] * rdx + rk[7] * rdy + rk[8] * rdz) * s2;
    }

    const H4* __restrict__ tbase = wsH + k * 4096;   // hoisted prim base

    float alpha = 0.f;
    float r0 = 0.f, r1 = 0.f, r2 = 0.f;   // per-lane rgb partials

    for (int i = 0; i < 64; ++i) {
        const float t = fmaf((float)i, kDT, tmin);
        const bool live = (t < tmax) && (alpha < 1.0f);
        if (__ballot(live) == 0ull) break;

        const float y0 = fmaf(D0, t, A0);
        const float y1 = fmaf(D1, t, A1);
        const float y2 = fmaf(D2, t, A2);
        const bool inside = live && fabsf(y0) <= 1.0f && fabsf(y1) <= 1.0f
                                 && fabsf(y2) <= 1.0f;
        if (__ballot(inside) == 0ull) continue;

        float s0 = 0.f, s1 = 0.f, s2 = 0.f, s3 = 0.f;
        if (inside) {
            // g in [0,15] guaranteed (single-rounded fma of a value in [0,15]).
            const float gz = fmaf(y0, 7.5f, 7.5f);
            const float gy = fmaf(y1, 7.5f, 7.5f);
            const float gx = fmaf(y2, 7.5f, 7.5f);
            const int iz = min((int)gz, 14);            // trunc == floor, g>=0
            const int iy = min((int)gy, 14);
            const int ix = min((int)gx, 14);
            const float fz = fminf(gz - (float)iz, 1.0f);
            const float fy = fminf(gy - (float)iy, 1.0f);
            const float fx = fminf(gx - (float)ix, 1.0f);

            const H4* tp = tbase + (iz * 256 + iy * 16 + ix);
            const H4 c000 = tp[0];
            const H4 c001 = tp[1];
            const H4 c010 = tp[16];
            const H4 c011 = tp[17];
            const H4 c100 = tp[256];
            const H4 c101 = tp[257];
            const H4 c110 = tp[272];
            const H4 c111 = tp[273];

            const __half2 hz = __float2half2_rn(fz);
            const __half2 hy = __float2half2_rn(fy);
            const __half2 hx = __float2half2_rn(fx);

            // factorized trilinear: z -> y -> x, on (r,g) and (b,a) pairs
            const __half2 m00l = lerp2(c000.lo, c100.lo, hz);
            const __half2 m00h = lerp2(c000.hi, c100.hi, hz);
            const __half2 m01l = lerp2(c001.lo, c101.lo, hz);
            const __half2 m01h = lerp2(c001.hi, c101.hi, hz);
            const __half2 m10l = lerp2(c010.lo, c110.lo, hz);
            const __half2 m10h = lerp2(c010.hi, c110.hi, hz);
            const __half2 m11l = lerp2(c011.lo, c111.lo, hz);
            const __half2 m11h = lerp2(c011.hi, c111.hi, hz);

            const __half2 n0l = lerp2(m00l, m10l, hy);
            const __half2 n0h = lerp2(m00h, m10h, hy);
            const __half2 n1l = lerp2(m01l, m11l, hy);
            const __half2 n1h = lerp2(m01h, m11h, hy);

            const __half2 vl = lerp2(n0l, n1l, hx);
            const __half2 vh = lerp2(n0h, n1h, hx);

            const float2 fLo = __half22float2(vl);
            const float2 fHi = __half22float2(vh);
            s0 = fLo.x; s1 = fLo.y; s2 = fHi.x; s3 = fHi.y;
        }

        // alpha-channel cross-lane reduce (masks < 32 stay within the half)
        float tot3 = s3;
        #pragma unroll
        for (int m = 1; m < 32; m <<= 1) tot3 += __shfl_xor(tot3, m);

        const float na = fminf(fmaf(tot3, kDT, alpha), 1.0f);  // tot3 >= 0
        const float contrib = na - alpha;
        alpha = na;
        r0 = fmaf(s0, contrib, r0);
        r1 = fmaf(s1, contrib, r1);
        r2 = fmaf(s2, contrib, r2);
    }

    #pragma unroll
    for (int m = 1; m < 32; m <<= 1) {
        r0 += __shfl_xor(r0, m);
        r1 += __shfl_xor(r1, m);
        r2 += __shfl_xor(r2, m);
    }

    if (k == 0) {
        out[0 * R + ray] = r0;
        out[1 * R + ray] = r1;
        out[2 * R + ray] = r2;
        out[3 * R + ray] = alpha;
        out[4 * R + ray] = r0;
        out[5 * R + ray] = r1;
        out[6 * R + ray] = r2;
        out[7 * R + ray] = alpha;
    }
}

// ---- fallback (round-6 kernel, original f32 template) for tiny ws ----
__global__ __launch_bounds__(256) void raymarch_fb(
    const float* __restrict__ raypos, const float* __restrict__ raydir,
    const float* __restrict__ tminmax, const float* __restrict__ primpos,
    const float* __restrict__ primrot, const float* __restrict__ primscale,
    const float* __restrict__ tmpl, float* __restrict__ out, int R)
{
    const int lane = threadIdx.x & 63;
    const int wid  = threadIdx.x >> 6;
    const int k    = lane & 31;
    const int half = lane >> 5;
    const int ray  = blockIdx.x * 8 + wid * 2 + half;

    const float rpx = raypos[ray*3+0], rpy = raypos[ray*3+1], rpz = raypos[ray*3+2];
    const float rdx = raydir[ray*3+0], rdy = raydir[ray*3+1], rdz = raydir[ray*3+2];
    const float tmin = tminmax[ray*2+0], tmax = tminmax[ray*2+1];

    float A0,A1,A2,D0,D1,D2;
    {
        const float ox = rpx - primpos[k*3+0], oy = rpy - primpos[k*3+1], oz = rpz - primpos[k*3+2];
        const float s0 = primscale[k*3+0], s1 = primscale[k*3+1], s2 = primscale[k*3+2];
        const float* rk = primrot + k*9;
        A0 = (rk[0]*ox+rk[1]*oy+rk[2]*oz)*s0; D0 = (rk[0]*rdx+rk[1]*rdy+rk[2]*rdz)*s0;
        A1 = (rk[3]*ox+rk[4]*oy+rk[5]*oz)*s1; D1 = (rk[3]*rdx+rk[4]*rdy+rk[5]*rdz)*s1;
        A2 = (rk[6]*ox+rk[7]*oy+rk[8]*oz)*s2; D2 = (rk[6]*rdx+rk[7]*rdy+rk[8]*rdz)*s2;
    }
    float alpha = 0.f, r0 = 0.f, r1 = 0.f, r2 = 0.f;
    for (int i = 0; i < 64; ++i) {
        const float t = fmaf((float)i, kDT, tmin);
        const bool live = (t < tmax) && (alpha < 1.0f);
        if (__ballot(live) == 0ull) break;
        const float y0 = fmaf(D0,t,A0), y1 = fmaf(D1,t,A1), y2 = fmaf(D2,t,A2);
        const bool inside = live && fabsf(y0)<=1.f && fabsf(y1)<=1.f && fabsf(y2)<=1.f;
        if (__ballot(inside) == 0ull) continue;
        float s0=0.f,s1=0.f,s2=0.f,s3=0.f;
        if (inside) {
            const float gz=(y0+1.f)*7.5f, gy=(y1+1.f)*7.5f, gx=(y2+1.f)*7.5f;
            const int iz=(int)fminf(floorf(gz),14.f), iy=(int)fminf(floorf(gy),14.f), ix=(int)fminf(floorf(gx),14.f);
            const float fz=fminf(gz-(float)iz,1.f), fy=fminf(gy-(float)iy,1.f), fx=fminf(gx-(float)ix,1.f);
            const float oz_=1.f-fz, oy_=1.f-fy, ox_=1.f-fx;
            const float w000=oz_*oy_*ox_, w001=oz_*oy_*fx, w010=oz_*fy*ox_, w011=oz_*fy*fx;
            const float w100=fz*oy_*ox_, w101=fz*oy_*fx, w110=fz*fy*ox_, w111=fz*fy*fx;
            const float* tp = tmpl + k*16384 + iz*256 + iy*16 + ix;
            float acc[4];
            #pragma unroll
            for (int c = 0; c < 4; ++c) {
                const float* tc = tp + c*4096;
                acc[c] = w000*tc[0]+w001*tc[1]+w010*tc[16]+w011*tc[17]
                       + w100*tc[256]+w101*tc[257]+w110*tc[272]+w111*tc[273];
            }
            s0=acc[0]; s1=acc[1]; s2=acc[2]; s3=acc[3];
        }
        float tot3 = s3;
        #pragma unroll
        for (int m = 1; m < 32; m <<= 1) tot3 += __shfl_xor(tot3, m);
        const float na = fminf(fmaf(tot3, kDT, alpha), 1.0f);
        const float contrib = na - alpha;
        alpha = na;
        r0 = fmaf(s0, contrib, r0); r1 = fmaf(s1, contrib, r1); r2 = fmaf(s2, contrib, r2);
    }
    #pragma unroll
    for (int m = 1; m < 32; m <<= 1) {
        r0 += __shfl_xor(r0, m); r1 += __shfl_xor(r1, m); r2 += __shfl_xor(r2, m);
    }
    if (k == 0) {
        out[0*R+ray]=r0; out[1*R+ray]=r1; out[2*R+ray]=r2; out[3*R+ray]=alpha;
        out[4*R+ray]=r0; out[5*R+ray]=r1; out[6*R+ray]=r2; out[7*R+ray]=alpha;
    }
}

} // namespace

extern "C" void kernel_launch(void* const* d_in, const int* in_sizes, int n_in,
                              void* d_out, int out_size, void* d_ws, size_t ws_size,
                              hipStream_t stream) {
    const float* raypos    = (const float*)d_in[0];
    const float* raydir    = (const float*)d_in[1];
    const float* tminmax   = (const float*)d_in[2];
    const float* primpos   = (const float*)d_in[3];
    const float* primrot   = (const float*)d_in[4];
    const float* primscale = (const float*)d_in[5];
    const float* tmpl      = (const float*)d_in[6];
    float* out = (float*)d_out;

    const int R = in_sizes[0] / 3;   // 16384
    const size_t needH = (size_t)kVox * sizeof(H4);   // 1 MiB

    if (ws_size >= needH) {
        H4* wsH = (H4*)d_ws;
        transpose_tmpl_h<<<dim3(kVox / 256), dim3(256), 0, stream>>>(tmpl, wsH);
        raymarch8<<<dim3(R / 8), dim3(256), 0, stream>>>(
            raypos, raydir, tminmax, primpos, primrot, primscale, wsH, out, R);
    } else {
        raymarch_fb<<<dim3(R / 8), dim3(256), 0, stream>>>(
            raypos, raydir, tminmax, primpos, primrot, primscale, tmpl, out, R);
    }
}

// Round 10
// 89.093 us; speedup vs baseline: 2.1208x; 1.0904x over previous
//
#include <hip/hip_runtime.h>
#include <hip/hip_fp16.h>

// Raymarcher: R=16384 rays, 64 steps, K=32 prims, template (32,4,16,16,16) f32.
// Round 10: 1 ray/wave, lane=(prim, step-parity): lanes 0-31 do step 2j,
// lanes 32-63 do step 2j+1 -> 32 iterations, uniform live/break branches,
// correlated-step skip gate. Exact 2-substep alpha chain via half-local reduce
// + one xor(32) exchange. Corner x-pairs loaded as one 16B load (4 VMEM/eval
// instead of 8). fp16 channel-last template + factorized lerp from r9.

namespace {

constexpr float kDT  = 1.0f / 64.0f;
constexpr int   kVox = 32 * 4096;   // (k,z,y,x) voxel count

struct H4 { __half2 lo, hi; };                                   // one voxel, 8 B
struct __attribute__((aligned(8))) H4x2 { __half2 l0, h0, l1, h1; }; // voxels (x, x+1), 16 B

// ---- pre-pass: (k,c,z,y,x) f32 -> (k,z,y,x,c) fp16 ----
__global__ __launch_bounds__(256) void transpose_tmpl_h(
    const float* __restrict__ tmpl, H4* __restrict__ wsH)
{
    const int idx = blockIdx.x * 256 + threadIdx.x;     // < 131072
    const int k   = idx >> 12;
    const int rem = idx & 4095;
    const float* src = tmpl + k * 16384 + rem;
    H4 v;
    v.lo = __floats2half2_rn(src[0],    src[4096]);
    v.hi = __floats2half2_rn(src[8192], src[12288]);
    wsH[idx] = v;
}

__device__ __forceinline__ __half2 lerp2(__half2 a, __half2 b, __half2 f) {
    return __hfma2(f, __hsub2(b, a), a);
}

__global__ __launch_bounds__(256) void raymarch9(
    const float* __restrict__ raypos,
    const float* __restrict__ raydir,
    const float* __restrict__ tminmax,
    const float* __restrict__ primpos,
    const float* __restrict__ primrot,
    const float* __restrict__ primscale,
    const H4* __restrict__ wsH,
    float* __restrict__ out,
    int R)
{
    const int lane   = threadIdx.x & 63;
    const int wid    = threadIdx.x >> 6;        // wave 0..3
    const int k      = lane & 31;               // prim owned by this lane
    const int parity = lane >> 5;               // step parity (0: even, 1: odd)
    const int ray    = blockIdx.x * 4 + wid;    // one ray per wave

    const float rpx = raypos[ray * 3 + 0];
    const float rpy = raypos[ray * 3 + 1];
    const float rpz = raypos[ray * 3 + 2];
    const float rdx = raydir[ray * 3 + 0];
    const float rdy = raydir[ray * 3 + 1];
    const float rdz = raydir[ray * 3 + 2];
    const float tmin = tminmax[ray * 2 + 0];
    const float tmax = tminmax[ray * 2 + 1];

    // Fold prim k into affine y_i(t) = A_i + D_i*t (verified r1-r9 math;
    // duplicated across the two parity halves).
    float A0, A1, A2, D0, D1, D2;
    {
        const float ox = rpx - primpos[k * 3 + 0];
        const float oy = rpy - primpos[k * 3 + 1];
        const float oz = rpz - primpos[k * 3 + 2];
        const float s0 = primscale[k * 3 + 0];
        const float s1 = primscale[k * 3 + 1];
        const float s2 = primscale[k * 3 + 2];
        const float* rk = primrot + k * 9;
        A0 = (rk[0] * ox + rk[1] * oy + rk[2] * oz) * s0;
        D0 = (rk[0] * rdx + rk[1] * rdy + rk[2] * rdz) * s0;
        A1 = (rk[3] * ox + rk[4] * oy + rk[5] * oz) * s1;
        D1 = (rk[3] * rdx + rk[4] * rdy + rk[5] * rdz) * s1;
        A2 = (rk[6] * ox + rk[7] * oy + rk[8] * oz) * s2;
        D2 = (rk[6] * rdx + rk[7] * rdy + rk[8] * rdz) * s2;
    }

    const H4* __restrict__ tbase = wsH + k * 4096;

    float alpha = 0.f;                      // wave-uniform
    float r0 = 0.f, r1 = 0.f, r2 = 0.f;     // per-lane rgb partials

    for (int j = 0; j < 32; ++j) {
        const float t0 = fmaf((float)(2 * j), kDT, tmin);      // even substep
        if (t0 >= tmax || alpha >= 1.0f) break;                // uniform branch

        const float tl = fmaf((float)(2 * j + parity), kDT, tmin);  // lane's t
        const float y0 = fmaf(D0, tl, A0);
        const float y1 = fmaf(D1, tl, A1);
        const float y2 = fmaf(D2, tl, A2);
        const bool inside = (tl < tmax) && fabsf(y0) <= 1.0f
                         && fabsf(y1) <= 1.0f && fabsf(y2) <= 1.0f;
        if (__ballot(inside) == 0ull) continue;   // both substeps empty

        float s0 = 0.f, s1 = 0.f, s2 = 0.f, s3 = 0.f;
        if (inside) {
            const float gz = fmaf(y0, 7.5f, 7.5f);   // in [0,15], single-rounded
            const float gy = fmaf(y1, 7.5f, 7.5f);
            const float gx = fmaf(y2, 7.5f, 7.5f);
            const int iz = min((int)gz, 14);          // trunc == floor, g>=0
            const int iy = min((int)gy, 14);
            const int ix = min((int)gx, 14);
            const float fz = fminf(gz - (float)iz, 1.0f);
            const float fy = fminf(gy - (float)iy, 1.0f);
            const float fx = fminf(gx - (float)ix, 1.0f);

            const H4* tp = tbase + (iz * 256 + iy * 16 + ix);
            const H4x2 p00 = *(const H4x2*)(tp + 0);    // (z0,y0,x0..x1)
            const H4x2 p01 = *(const H4x2*)(tp + 16);   // (z0,y1,x0..x1)
            const H4x2 p10 = *(const H4x2*)(tp + 256);  // (z1,y0,x0..x1)
            const H4x2 p11 = *(const H4x2*)(tp + 272);  // (z1,y1,x0..x1)

            const __half2 hz = __float2half2_rn(fz);
            const __half2 hy = __float2half2_rn(fy);
            const __half2 hx = __float2half2_rn(fx);

            // factorized trilinear: z -> y -> x on (r,g)/(b,a) packed pairs
            const __half2 q0l0 = lerp2(p00.l0, p10.l0, hz);
            const __half2 q0h0 = lerp2(p00.h0, p10.h0, hz);
            const __half2 q0l1 = lerp2(p00.l1, p10.l1, hz);
            const __half2 q0h1 = lerp2(p00.h1, p10.h1, hz);
            const __half2 q1l0 = lerp2(p01.l0, p11.l0, hz);
            const __half2 q1h0 = lerp2(p01.h0, p11.h0, hz);
            const __half2 q1l1 = lerp2(p01.l1, p11.l1, hz);
            const __half2 q1h1 = lerp2(p01.h1, p11.h1, hz);

            const __half2 ul0 = lerp2(q0l0, q1l0, hy);
            const __half2 uh0 = lerp2(q0h0, q1h0, hy);
            const __half2 ul1 = lerp2(q0l1, q1l1, hy);
            const __half2 uh1 = lerp2(q0h1, q1h1, hy);

            const __half2 vl = lerp2(ul0, ul1, hx);
            const __half2 vh = lerp2(uh0, uh1, hx);

            const float2 fLo = __half22float2(vl);
            const float2 fHi = __half22float2(vh);
            s0 = fLo.x; s1 = fLo.y; s2 = fHi.x; s3 = fHi.y;
        }

        // half-local alpha reduce (xor masks 1..16 stay within each half)
        float tot = s3;
        #pragma unroll
        for (int m = 1; m < 32; m <<= 1) tot += __shfl_xor(tot, m);
        const float other = __shfl_xor(tot, 32);
        const float te = parity ? other : tot;    // even-substep total
        const float to = parity ? tot : other;    // odd-substep total

        // exact 2-substep alpha chain (totals >= 0 => clip == min)
        const float t1v = fmaf((float)(2 * j + 1), kDT, tmin);
        const float a_e = te * kDT;                              // t0 < tmax held
        const float a_o = (t1v < tmax) ? to * kDT : 0.0f;
        const float na1 = fminf(alpha + a_e, 1.0f);
        const float c_e = na1 - alpha;
        const float na2 = fminf(na1 + a_o, 1.0f);
        const float c_o = na2 - na1;
        alpha = na2;

        const float contrib = parity ? c_o : c_e;
        r0 = fmaf(s0, contrib, r0);
        r1 = fmaf(s1, contrib, r1);
        r2 = fmaf(s2, contrib, r2);
    }

    // full-wave rgb reduce (both parity halves contributed)
    #pragma unroll
    for (int m = 1; m < 64; m <<= 1) {
        r0 += __shfl_xor(r0, m);
        r1 += __shfl_xor(r1, m);
        r2 += __shfl_xor(r2, m);
    }

    if (lane == 0) {
        out[0 * R + ray] = r0;
        out[1 * R + ray] = r1;
        out[2 * R + ray] = r2;
        out[3 * R + ray] = alpha;
        out[4 * R + ray] = r0;
        out[5 * R + ray] = r1;
        out[6 * R + ray] = r2;
        out[7 * R + ray] = alpha;
    }
}

// ---- fallback (r6-style, original f32 template) for tiny ws ----
__global__ __launch_bounds__(256) void raymarch_fb(
    const float* __restrict__ raypos, const float* __restrict__ raydir,
    const float* __restrict__ tminmax, const float* __restrict__ primpos,
    const float* __restrict__ primrot, const float* __restrict__ primscale,
    const float* __restrict__ tmpl, float* __restrict__ out, int R)
{
    const int lane = threadIdx.x & 63;
    const int wid  = threadIdx.x >> 6;
    const int k    = lane & 31;
    const int half = lane >> 5;
    const int ray  = blockIdx.x * 8 + wid * 2 + half;

    const float rpx = raypos[ray*3+0], rpy = raypos[ray*3+1], rpz = raypos[ray*3+2];
    const float rdx = raydir[ray*3+0], rdy = raydir[ray*3+1], rdz = raydir[ray*3+2];
    const float tmin = tminmax[ray*2+0], tmax = tminmax[ray*2+1];

    float A0,A1,A2,D0,D1,D2;
    {
        const float ox = rpx - primpos[k*3+0], oy = rpy - primpos[k*3+1], oz = rpz - primpos[k*3+2];
        const float s0 = primscale[k*3+0], s1 = primscale[k*3+1], s2 = primscale[k*3+2];
        const float* rk = primrot + k*9;
        A0 = (rk[0]*ox+rk[1]*oy+rk[2]*oz)*s0; D0 = (rk[0]*rdx+rk[1]*rdy+rk[2]*rdz)*s0;
        A1 = (rk[3]*ox+rk[4]*oy+rk[5]*oz)*s1; D1 = (rk[3]*rdx+rk[4]*rdy+rk[5]*rdz)*s1;
        A2 = (rk[6]*ox+rk[7]*oy+rk[8]*oz)*s2; D2 = (rk[6]*rdx+rk[7]*rdy+rk[8]*rdz)*s2;
    }
    float alpha = 0.f, r0 = 0.f, r1 = 0.f, r2 = 0.f;
    for (int i = 0; i < 64; ++i) {
        const float t = fmaf((float)i, kDT, tmin);
        const bool live = (t < tmax) && (alpha < 1.0f);
        if (__ballot(live) == 0ull) break;
        const float y0 = fmaf(D0,t,A0), y1 = fmaf(D1,t,A1), y2 = fmaf(D2,t,A2);
        const bool inside = live && fabsf(y0)<=1.f && fabsf(y1)<=1.f && fabsf(y2)<=1.f;
        if (__ballot(inside) == 0ull) continue;
        float s0=0.f,s1=0.f,s2=0.f,s3=0.f;
        if (inside) {
            const float gz=(y0+1.f)*7.5f, gy=(y1+1.f)*7.5f, gx=(y2+1.f)*7.5f;
            const int iz=(int)fminf(floorf(gz),14.f), iy=(int)fminf(floorf(gy),14.f), ix=(int)fminf(floorf(gx),14.f);
            const float fz=fminf(gz-(float)iz,1.f), fy=fminf(gy-(float)iy,1.f), fx=fminf(gx-(float)ix,1.f);
            const float oz_=1.f-fz, oy_=1.f-fy, ox_=1.f-fx;
            const float w000=oz_*oy_*ox_, w001=oz_*oy_*fx, w010=oz_*fy*ox_, w011=oz_*fy*fx;
            const float w100=fz*oy_*ox_, w101=fz*oy_*fx, w110=fz*fy*ox_, w111=fz*fy*fx;
            const float* tp = tmpl + k*16384 + iz*256 + iy*16 + ix;
            float acc[4];
            #pragma unroll
            for (int c = 0; c < 4; ++c) {
                const float* tc = tp + c*4096;
                acc[c] = w000*tc[0]+w001*tc[1]+w010*tc[16]+w011*tc[17]
                       + w100*tc[256]+w101*tc[257]+w110*tc[272]+w111*tc[273];
            }
            s0=acc[0]; s1=acc[1]; s2=acc[2]; s3=acc[3];
        }
        float tot3 = s3;
        #pragma unroll
        for (int m = 1; m < 32; m <<= 1) tot3 += __shfl_xor(tot3, m);
        const float na = fminf(fmaf(tot3, kDT, alpha), 1.0f);
        const float contrib = na - alpha;
        alpha = na;
        r0 = fmaf(s0, contrib, r0); r1 = fmaf(s1, contrib, r1); r2 = fmaf(s2, contrib, r2);
    }
    #pragma unroll
    for (int m = 1; m < 32; m <<= 1) {
        r0 += __shfl_xor(r0, m); r1 += __shfl_xor(r1, m); r2 += __shfl_xor(r2, m);
    }
    if (k == 0) {
        out[0*R+ray]=r0; out[1*R+ray]=r1; out[2*R+ray]=r2; out[3*R+ray]=alpha;
        out[4*R+ray]=r0; out[5*R+ray]=r1; out[6*R+ray]=r2; out[7*R+ray]=alpha;
    }
}

} // namespace

extern "C" void kernel_launch(void* const* d_in, const int* in_sizes, int n_in,
                              void* d_out, int out_size, void* d_ws, size_t ws_size,
                              hipStream_t stream) {
    const float* raypos    = (const float*)d_in[0];
    const float* raydir    = (const float*)d_in[1];
    const float* tminmax   = (const float*)d_in[2];
    const float* primpos   = (const float*)d_in[3];
    const float* primrot   = (const float*)d_in[4];
    const float* primscale = (const float*)d_in[5];
    const float* tmpl      = (const float*)d_in[6];
    float* out = (float*)d_out;

    const int R = in_sizes[0] / 3;   // 16384
    const size_t needH = (size_t)kVox * sizeof(H4);   // 1 MiB

    if (ws_size >= needH) {
        H4* wsH = (H4*)d_ws;
        transpose_tmpl_h<<<dim3(kVox / 256), dim3(256), 0, stream>>>(tmpl, wsH);
        raymarch9<<<dim3(R / 4), dim3(256), 0, stream>>>(
            raypos, raydir, tminmax, primpos, primrot, primscale, wsH, out, R);
    } else {
        raymarch_fb<<<dim3(R / 8), dim3(256), 0, stream>>>(
            raypos, raydir, tminmax, primpos, primrot, primscale, tmpl, out, R);
    }
}